// Round 13
// baseline (111.431 us; speedup 1.0000x reference)
//
#include <hip/hip_runtime.h>
#include <hip/hip_bf16.h>

#define NB 8
#define NT 2048
#define NH 4
#define NF 256
#define NTF 768
#define NM (NB * NT)   // 16384

typedef unsigned short u16;
typedef unsigned int u32;
typedef unsigned long long u64;
typedef u16 u16x8 __attribute__((ext_vector_type(8)));
typedef __bf16 bf16x8 __attribute__((ext_vector_type(8)));
typedef float f32x4 __attribute__((ext_vector_type(4)));
typedef float f32x16 __attribute__((ext_vector_type(16)));

__device__ __forceinline__ u16 bf16_rne(float f) {
    union { float f; unsigned u; } x; x.f = f;
    unsigned u = x.u;
    return (u16)((u + 0x7fffu + ((u >> 16) & 1u)) >> 16);
}

// byte offset into a [rows][128B] LDS tile with XOR swizzle
__device__ __forceinline__ int swz(int row, int colB) {
    return row * 128 + (colB ^ ((row & 7) << 4));
}

// async global->LDS, 16B per lane; LDS dest = wave-uniform base + lane*16
__device__ __forceinline__ void glds16(const void* g, void* l) {
    __builtin_amdgcn_global_load_lds(
        (const __attribute__((address_space(1))) void*)g,
        (__attribute__((address_space(3))) void*)l, 16, 0, 0);
}

__device__ __forceinline__ u32 pkbf16(float lo, float hi) {
    union { __bf16 h2[2]; u32 u; } t;
    t.h2[0] = (__bf16)lo; t.h2[1] = (__bf16)hi;
    return t.u;
}

// v_permlane32_swap: out a = {a[0:31], b_from_lower}, b = {a_from_upper, b[32:63]}
__device__ __forceinline__ void pl32swap(u32& a, u32& b) {
    asm("v_permlane32_swap_b32 %0, %1" : "+v"(a), "+v"(b));
}

#define mfma16(A, B, C) __builtin_amdgcn_mfma_f32_16x16x32_bf16((A), (B), (C), 0, 0, 0)
#define mfma32(A, B, C) __builtin_amdgcn_mfma_f32_32x32x16_bf16((A), (B), (C), 0, 0, 0)

// ---------------------------------------------------------------- converts
__global__ __launch_bounds__(256) void convert_all_kernel(
        const float* __restrict__ q, const float* __restrict__ k,
        const float* __restrict__ v, const float* __restrict__ wqkv,
        const float* __restrict__ wout, const int* __restrict__ mask,
        u16* __restrict__ xcat, u16* __restrict__ wqkvb,
        u16* __restrict__ woutb, float* __restrict__ maskadd) {
    int bid = blockIdx.x;
    if (bid < 6144) {
        int tid = bid * 256 + threadIdx.x;
        int row = tid / 96;
        int c8  = (tid % 96) * 8;
        const float* src; int c;
        if (c8 < NF)            { src = q; c = c8; }
        else if (c8 < 2 * NF)   { src = k; c = c8 - NF; }
        else                    { src = v; c = c8 - 2 * NF; }
        const float4* p = reinterpret_cast<const float4*>(src + (size_t)row * NF + c);
        float4 a = p[0], b = p[1];
        u16x8 o;
        o[0] = bf16_rne(a.x); o[1] = bf16_rne(a.y); o[2] = bf16_rne(a.z); o[3] = bf16_rne(a.w);
        o[4] = bf16_rne(b.x); o[5] = bf16_rne(b.y); o[6] = bf16_rne(b.z); o[7] = bf16_rne(b.w);
        *reinterpret_cast<u16x8*>(xcat + (size_t)row * NTF + c8) = o;
    } else if (bid < 6464) {
        int tid = (bid - 6144) * 256 + threadIdx.x;
        int i8 = tid * 8;
        const float* src; u16* dst; int off;
        if (i8 < NTF * NTF) { src = wqkv; dst = wqkvb; off = i8; }
        else                { src = wout; dst = woutb; off = i8 - NTF * NTF; }
        const float4* p = reinterpret_cast<const float4*>(src + off);
        float4 a = p[0], b = p[1];
        u16x8 o;
        o[0] = bf16_rne(a.x); o[1] = bf16_rne(a.y); o[2] = bf16_rne(a.z); o[3] = bf16_rne(a.w);
        o[4] = bf16_rne(b.x); o[5] = bf16_rne(b.y); o[6] = bf16_rne(b.z); o[7] = bf16_rne(b.w);
        *reinterpret_cast<u16x8*>(dst + off) = o;
    } else {
        int i = (bid - 6464) * 2048 + threadIdx.x * 8;
        int4 m0 = *reinterpret_cast<const int4*>(mask + i);
        int4 m1 = *reinterpret_cast<const int4*>(mask + i + 4);
        float4 f0 = { m0.x ? 0.f : -1e30f, m0.y ? 0.f : -1e30f,
                      m0.z ? 0.f : -1e30f, m0.w ? 0.f : -1e30f };
        float4 f1 = { m1.x ? 0.f : -1e30f, m1.y ? 0.f : -1e30f,
                      m1.z ? 0.f : -1e30f, m1.w ? 0.f : -1e30f };
        *reinterpret_cast<float4*>(maskadd + i) = f0;
        *reinterpret_cast<float4*>(maskadd + i + 4) = f1;
    }
}

// ---------------------------------------------------------------- 128x128 GEMM
// C(MxN) = A(MxK, bf16) * W(NxK)^T + bias. BK=64, 4 waves (2x2), 16x16x32
// MFMA, glds16 dbuf, 1 barrier/k-step. MODE 1: fp32 row-major out.
// MODE 2 (QKV): V 64-col groups scatter transposed to Vt; Q/K row-major u16.
template<int N, int K, int MODE>
__global__ __launch_bounds__(256) void gemm128_kernel(
        const u16* __restrict__ A, const u16* __restrict__ Bw,
        const float* __restrict__ bias, void* __restrict__ Cout,
        u16* __restrict__ Vt) {
    __shared__ alignas(16) char smem[65536];
    char* As = smem;            // 2 x 16KB
    char* Bs = smem + 32768;    // 2 x 16KB
    int m0 = blockIdx.x * 128, n0 = blockIdx.y * 128;
    int tid = threadIdx.x;
    int w = tid >> 6, lane = tid & 63, l15 = lane & 15, hi = lane >> 4;
    int wr = w >> 1, wc = w & 1;
    int r0 = tid >> 3, cb0 = (tid & 7) * 16;       // staging: 32 rows/pass
    int gcb = cb0 ^ ((r0 & 7) << 4);               // pre-swizzled source col-byte
    int wo = w * 1024;

    const char* Ac = (const char*)A;
    const char* Bc = (const char*)Bw;
    const char* gA = Ac + (size_t)(m0 + r0) * (K * 2) + gcb;   // + p*32 rows
    const char* gB = Bc + (size_t)(n0 + r0) * (K * 2) + gcb;
    const size_t rstep = (size_t)32 * (K * 2);     // 32-row pass stride

    // prologue: stage kt=0 into buf 0 (4 passes each for A and B)
#pragma unroll
    for (int p = 0; p < 4; ++p) {
        glds16(gA + p * rstep, As + p * 4096 + wo);
        glds16(gB + p * rstep, Bs + p * 4096 + wo);
    }

    f32x4 acc[4][4];
#pragma unroll
    for (int fi = 0; fi < 4; ++fi)
#pragma unroll
        for (int fj = 0; fj < 4; ++fj) acc[fi][fj] = (f32x4){0.f, 0.f, 0.f, 0.f};

    constexpr int NKT = K / 64;
    for (int kt = 0; kt < NKT; ++kt) {
        int cur = kt & 1;
        __syncthreads();                           // drain glds(kt) + prior reads
        if (kt + 1 < NKT) {
            int off = (kt + 1) * 128;
            char* Ad = As + (cur ^ 1) * 16384;
            char* Bd = Bs + (cur ^ 1) * 16384;
#pragma unroll
            for (int p = 0; p < 4; ++p) {
                glds16(gA + p * rstep + off, Ad + p * 4096 + wo);
                glds16(gB + p * rstep + off, Bd + p * 4096 + wo);
            }
        }
        const char* Ax = As + cur * 16384;
        const char* Bx = Bs + cur * 16384;
#pragma unroll
        for (int ks = 0; ks < 2; ++ks) {
            bf16x8 af[4], bf[4];
#pragma unroll
            for (int fi = 0; fi < 4; ++fi)
                af[fi] = *reinterpret_cast<const bf16x8*>(
                    Ax + swz(wr * 64 + fi * 16 + l15, hi * 16 + ks * 64));
#pragma unroll
            for (int fj = 0; fj < 4; ++fj)
                bf[fj] = *reinterpret_cast<const bf16x8*>(
                    Bx + swz(wc * 64 + fj * 16 + l15, hi * 16 + ks * 64));
#pragma unroll
            for (int fi = 0; fi < 4; ++fi)
#pragma unroll
                for (int fj = 0; fj < 4; ++fj)
                    acc[fi][fj] = mfma16(af[fi], bf[fj], acc[fi][fj]);
        }
    }

    // epilogue
    int rowBase = m0 + wr * 64;        // 64-aligned; never crosses a batch
    if constexpr (MODE == 2) {
        int g64 = (n0 >> 6) + wc;      // 64-col group 0..11
        int typ = g64 % 3, h = g64 / 3;
        if (typ == 2) {
            int b = rowBase >> 11;
            int bh = b * NH + h;
#pragma unroll
            for (int fi = 0; fi < 4; ++fi) {
                int t = (rowBase + fi * 16 + hi * 4) & (NT - 1);
#pragma unroll
                for (int fj = 0; fj < 4; ++fj) {
                    int d = fj * 16 + l15;
                    float bv = bias[n0 + wc * 64 + d];
                    u32 lo = pkbf16(acc[fi][fj][0] + bv, acc[fi][fj][1] + bv);
                    u32 hi2 = pkbf16(acc[fi][fj][2] + bv, acc[fi][fj][3] + bv);
                    u64 pk = (u64)lo | ((u64)hi2 << 32);
                    *reinterpret_cast<u64*>(Vt + (size_t)(bh * 64 + d) * NT + t) = pk;
                }
            }
        } else {
#pragma unroll
            for (int fi = 0; fi < 4; ++fi) {
                int orow = rowBase + fi * 16 + hi * 4;
#pragma unroll
                for (int fj = 0; fj < 4; ++fj) {
                    int col = n0 + wc * 64 + fj * 16 + l15;
                    float bv = bias[col];
#pragma unroll
                    for (int r = 0; r < 4; ++r)
                        reinterpret_cast<u16*>(Cout)[(size_t)(orow + r) * N + col] =
                            bf16_rne(acc[fi][fj][r] + bv);
                }
            }
        }
    } else {
#pragma unroll
        for (int fi = 0; fi < 4; ++fi) {
            int orow = rowBase + fi * 16 + hi * 4;
#pragma unroll
            for (int fj = 0; fj < 4; ++fj) {
                int col = n0 + wc * 64 + fj * 16 + l15;
                float bv = bias[col];
#pragma unroll
                for (int r = 0; r < 4; ++r)
                    reinterpret_cast<float*>(Cout)[(size_t)(orow + r) * N + col] =
                        acc[fi][fj][r] + bv;
            }
        }
    }
}

// ---------------------------------------------------------------- attention
// grid (B*H, T/64): QBLK=64, 1024 blocks, 4 waves (wq=w&1 q-subtile, g=w>>1
// key half). 32x32x16 MFMA; swapped QK^T; P in registers; fixed-offset exp2
// softmax. T4 pipeline: 3 LDS buffers (48KB -> 3 blocks/CU), prefetch 2 tiles
// ahead, raw s_barrier with counted vmcnt (8 steady / 4 edges) so glds stay
// in flight across barriers. Mask register-prefetched one tile ahead.
__global__ __launch_bounds__(256, 3) void attn_kernel(
        const u16* __restrict__ qkv, const u16* __restrict__ vt,
        const float* __restrict__ maskadd, u16* __restrict__ xout) {
    int bh = blockIdx.x;
    int q0 = blockIdx.y * 64;
    int b = bh >> 2, h = bh & 3;
    // K: 3 x 8KB at [0,24576); V: 3 x 8KB at [24576,49152)
    __shared__ alignas(16) char smem[49152];
    int tid = threadIdx.x;
    int w = tid >> 6, lane = tid & 63;
    int l31 = lane & 31, hv = lane >> 5;
    int wq = w & 1, g = w >> 1;
    int r0 = tid >> 3, cb0 = (tid & 7) * 16;
    int gcb = cb0 ^ ((r0 & 7) << 4);
    int wo = w * 1024;
    const float SCALE = 0.125f * 1.44269504088896340736f;  // 1/sqrt(dk)*log2e

    const char* qkvC = (const char*)qkv;
    const char* vtC  = (const char*)vt;
    const char* gk0 = qkvC + (size_t)(b * NT + r0) * 1536 + h * 384 + 128 + gcb;
    const char* gv0 = vtC + (size_t)(bh * 64 + r0) * (NT * 2) + gcb;
    const float* gm = maskadd + (size_t)b * NT;

    auto stage = [&](int t) {    // one 64-key tile: 4 glds (K rows, V rows)
        char* Kd = smem + (t % 3) * 8192;
        char* Vd = smem + 24576 + (t % 3) * 8192;
        size_t ko = (size_t)t * 98304, vo2 = (size_t)t * 128;
        glds16(gk0 + ko,                      Kd + wo);
        glds16(gk0 + ko + (size_t)32 * 1536,  Kd + 4096 + wo);
        glds16(gv0 + vo2,                     Vd + wo);
        glds16(gv0 + vo2 + (size_t)32 * 4096, Vd + 4096 + wo);
    };

    // Q fragments straight from global (issued first -> oldest in vmcnt)
    const char* qrow = qkvC + (size_t)(b * NT + q0 + wq * 32 + l31) * 1536
                       + h * 384 + hv * 16;
    bf16x8 bQ0 = *reinterpret_cast<const bf16x8*>(qrow);
    bf16x8 bQ1 = *reinterpret_cast<const bf16x8*>(qrow + 32);
    bf16x8 bQ2 = *reinterpret_cast<const bf16x8*>(qrow + 64);
    bf16x8 bQ3 = *reinterpret_cast<const bf16x8*>(qrow + 96);

    // prologue: mask(0) -> regs, then stage tiles 0,1
    f32x4 mcur[4], mnext[4];
#pragma unroll
    for (int rq = 0; rq < 4; ++rq)
        mcur[rq] = *reinterpret_cast<const f32x4*>(gm + g * 32 + rq * 8 + 4 * hv);
    stage(0);
    stage(1);

    f32x16 accO0 = 0.f, accO1 = 0.f;   // O^T[d 0..31][q], O^T[d 32..63][q]
    float ssum = 0.f;

    for (int j = 0; j < NT / 64; ++j) {
        // counted-vmcnt barrier: retire set(j) (+ older), keep newer in flight.
        // chronology: ... set(j)@j-2, mask(j)@j-1, set(j+1)@j-1  -> newer=8.
        // j=0: newer-than-set(0) = set(1) = 4.  j=31: newer = mask(31) = 4.
        if (j == 0 || j == NT / 64 - 1)
            asm volatile("s_waitcnt vmcnt(4)" ::: "memory");
        else
            asm volatile("s_waitcnt vmcnt(8)" ::: "memory");
        __builtin_amdgcn_s_barrier();
        __builtin_amdgcn_sched_barrier(0);

        if (j < NT / 64 - 1) {
#pragma unroll
            for (int rq = 0; rq < 4; ++rq)
                mnext[rq] = *reinterpret_cast<const f32x4*>(
                    gm + (j + 1) * 64 + g * 32 + rq * 8 + 4 * hv);
        }
        if (j < NT / 64 - 2) stage(j + 2);

        const char* Kx = smem + (j % 3) * 8192;
        const char* Vx = smem + 24576 + (j % 3) * 8192;

        // ---- QK for this wave's 32-key half: S^T[key = g*32 + 8rq+4hv+e][q=l31]
        f32x16 s = 0.f;
        __builtin_amdgcn_s_setprio(1);
#pragma unroll
        for (int ks = 0; ks < 4; ++ks) {
            bf16x8 a = *reinterpret_cast<const bf16x8*>(
                Kx + swz(g * 32 + l31, ks * 32 + hv * 16));
            bf16x8 bq = (ks == 0) ? bQ0 : (ks == 1) ? bQ1 : (ks == 2) ? bQ2 : bQ3;
            s = mfma32(a, bq, s);
        }
        __builtin_amdgcn_s_setprio(0);

        // ---- softmax: p = 2^(s*SCALE + madd[key]) using register mask
#pragma unroll
        for (int rq = 0; rq < 4; ++rq) {
#pragma unroll
            for (int e = 0; e < 4; ++e)
                s[rq * 4 + e] = __builtin_amdgcn_exp2f(
                    __builtin_fmaf(s[rq * 4 + e], SCALE, mcur[rq][e]));
        }
        {   // per-lane partial row-sum (q = l31 fixed per lane)
            union { f32x16 v; f32x4 q[4]; } u; u.v = s;
            f32x4 r4 = (u.q[0] + u.q[1]) + (u.q[2] + u.q[3]);
            ssum += (r4[0] + r4[1]) + (r4[2] + r4[3]);
        }
        // ---- pack P; build B-operands via permlane32_swap; PV MFMA
        u32 pa[4], pb[4];
#pragma unroll
        for (int rq = 0; rq < 4; ++rq) {
            pa[rq] = pkbf16(s[rq * 4 + 0], s[rq * 4 + 1]);
            pb[rq] = pkbf16(s[rq * 4 + 2], s[rq * 4 + 3]);
        }
        __builtin_amdgcn_s_setprio(1);
#pragma unroll
        for (int sp2 = 0; sp2 < 2; ++sp2) {
            const int sp = sp2 * 2;
            u32 B0 = pa[sp], B2 = pa[sp + 1], B1 = pb[sp], B3 = pb[sp + 1];
            pl32swap(B0, B2);   // -> keys +{0,1} / +{4,5} in every lane
            pl32swap(B1, B3);   // -> keys +{2,3} / +{6,7}
            union { u32 u4[4]; bf16x8 v; } bp;
            bp.u4[0] = B0; bp.u4[1] = B1; bp.u4[2] = B2; bp.u4[3] = B3;
            int s4 = 2 * g + sp2;
            bf16x8 av0 = *reinterpret_cast<const bf16x8*>(
                Vx + swz(l31, s4 * 32 + hv * 16));
            bf16x8 av1 = *reinterpret_cast<const bf16x8*>(
                Vx + swz(32 + l31, s4 * 32 + hv * 16));
            accO0 = mfma32(av0, bp.v, accO0);
            accO1 = mfma32(av1, bp.v, accO1);
        }
        __builtin_amdgcn_s_setprio(0);
#pragma unroll
        for (int rq = 0; rq < 4; ++rq) mcur[rq] = mnext[rq];
    }

    // ---- combine key-half pairs: g=1 hands partials to g=0 via LDS
    ssum += __shfl_xor(ssum, 32, 64);
    __syncthreads();   // full drain; K region now reusable for partials
    float* sS = reinterpret_cast<float*>(smem + 16384);
    if (g == 1) {
        union { f32x16 v; f32x4 q[4]; } o0, o1; o0.v = accO0; o1.v = accO1;
#pragma unroll
        for (int i = 0; i < 4; ++i) {
            *reinterpret_cast<f32x4*>(smem + wq * 8192 + i * 1024 + lane * 16) = o0.q[i];
            *reinterpret_cast<f32x4*>(smem + wq * 8192 + (4 + i) * 1024 + lane * 16) = o1.q[i];
        }
        if (lane < 32) sS[wq * 32 + l31] = ssum;
    }
    __syncthreads();
    if (g == 0) {
        union { f32x16 v; f32x4 q[4]; } o0, o1; o0.v = accO0; o1.v = accO1;
#pragma unroll
        for (int i = 0; i < 4; ++i) {
            o0.q[i] += *reinterpret_cast<const f32x4*>(smem + wq * 8192 + i * 1024 + lane * 16);
            o1.q[i] += *reinterpret_cast<const f32x4*>(smem + wq * 8192 + (4 + i) * 1024 + lane * 16);
        }
        float stot = ssum + sS[wq * 32 + l31];
        float inv = stot > 0.f ? 1.0f / stot : 0.0f;
        int qg = b * NT + q0 + wq * 32 + l31;
        const float* of0 = (const float*)&o0.v;
        const float* of1 = (const float*)&o1.v;
#pragma unroll
        for (int db = 0; db < 2; ++db) {
            const float* of = db ? of1 : of0;
#pragma unroll
            for (int rq = 0; rq < 4; ++rq) {
                u32 lo = pkbf16(of[rq * 4 + 0] * inv, of[rq * 4 + 1] * inv);
                u32 hi2 = pkbf16(of[rq * 4 + 2] * inv, of[rq * 4 + 3] * inv);
                u64 pk = (u64)lo | ((u64)hi2 << 32);
                int d = db * 32 + rq * 8 + 4 * hv;
                *reinterpret_cast<u64*>(xout + (size_t)qg * NF + h * 64 + d) = pk;
            }
        }
    }
}

// ---------------------------------------------------------------- launch
extern "C" void kernel_launch(void* const* d_in, const int* in_sizes, int n_in,
                              void* d_out, int out_size, void* d_ws, size_t ws_size,
                              hipStream_t stream) {
    const float* q    = (const float*)d_in[0];
    const float* k    = (const float*)d_in[1];
    const float* v    = (const float*)d_in[2];
    const int*   mask = (const int*)d_in[3];
    const float* wqkv = (const float*)d_in[4];
    const float* bqkv = (const float*)d_in[5];
    const float* wout = (const float*)d_in[6];
    const float* bout = (const float*)d_in[7];
    float* out = (float*)d_out;

    char* ws = (char*)d_ws;
    u16*   Xcat    = (u16*)(ws);                   // 25,165,824 B
    u16*   QKV     = (u16*)(ws + 25165824);        // 25,165,824 B (V cols unused)
    u16*   Vt      = (u16*)(ws + 50331648);        //  8,388,608 B
    u16*   Xattn   = (u16*)(ws + 58720256);        //  8,388,608 B
    u16*   Wqkvb   = (u16*)(ws + 67108864);        //  1,179,648 B
    u16*   Woutb   = (u16*)(ws + 68288512);        //    131,072 B
    float* Maskadd = (float*)(ws + 68419584);      //     65,536 B

    convert_all_kernel<<<6472, 256, 0, stream>>>(q, k, v, wqkv, wout, mask,
                                                 Xcat, Wqkvb, Woutb, Maskadd);
    gemm128_kernel<NTF, NTF, 2><<<dim3(NM / 128, NTF / 128), 256, 0, stream>>>(
        Xcat, Wqkvb, bqkv, QKV, Vt);
    attn_kernel<<<dim3(NB * NH, NT / 64), 256, 0, stream>>>(QKV, Vt, Maskadd, Xattn);
    gemm128_kernel<NF, NF, 1><<<dim3(NM / 128, NF / 128), 256, 0, stream>>>(
        Xattn, Woutb, bout, out, nullptr);
}

// Round 14
// 107.087 us; speedup vs baseline: 1.0406x; 1.0406x over previous
//
#include <hip/hip_runtime.h>
#include <hip/hip_bf16.h>

#define NB 8
#define NT 2048
#define NH 4
#define NF 256
#define NTF 768
#define NM (NB * NT)   // 16384

typedef unsigned short u16;
typedef unsigned int u32;
typedef unsigned long long u64;
typedef u16 u16x8 __attribute__((ext_vector_type(8)));
typedef __bf16 bf16x8 __attribute__((ext_vector_type(8)));
typedef float f32x4 __attribute__((ext_vector_type(4)));
typedef float f32x16 __attribute__((ext_vector_type(16)));

__device__ __forceinline__ u16 bf16_rne(float f) {
    union { float f; unsigned u; } x; x.f = f;
    unsigned u = x.u;
    return (u16)((u + 0x7fffu + ((u >> 16) & 1u)) >> 16);
}

// byte offset into a [rows][128B] LDS tile with XOR swizzle
__device__ __forceinline__ int swz(int row, int colB) {
    return row * 128 + (colB ^ ((row & 7) << 4));
}

// async global->LDS, 16B per lane; LDS dest = wave-uniform base + lane*16
__device__ __forceinline__ void glds16(const void* g, void* l) {
    __builtin_amdgcn_global_load_lds(
        (const __attribute__((address_space(1))) void*)g,
        (__attribute__((address_space(3))) void*)l, 16, 0, 0);
}

__device__ __forceinline__ u32 pkbf16(float lo, float hi) {
    union { __bf16 h2[2]; u32 u; } t;
    t.h2[0] = (__bf16)lo; t.h2[1] = (__bf16)hi;
    return t.u;
}

// v_permlane32_swap: out a = {a[0:31], b_from_lower}, b = {a_from_upper, b[32:63]}
__device__ __forceinline__ void pl32swap(u32& a, u32& b) {
    asm("v_permlane32_swap_b32 %0, %1" : "+v"(a), "+v"(b));
}

#define mfma16(A, B, C) __builtin_amdgcn_mfma_f32_16x16x32_bf16((A), (B), (C), 0, 0, 0)
#define mfma32(A, B, C) __builtin_amdgcn_mfma_f32_32x32x16_bf16((A), (B), (C), 0, 0, 0)

// ---------------------------------------------------------------- converts
__global__ __launch_bounds__(256) void convert_all_kernel(
        const float* __restrict__ q, const float* __restrict__ k,
        const float* __restrict__ v, const float* __restrict__ wqkv,
        const float* __restrict__ wout, const int* __restrict__ mask,
        u16* __restrict__ xcat, u16* __restrict__ wqkvb,
        u16* __restrict__ woutb, float* __restrict__ maskadd) {
    int bid = blockIdx.x;
    if (bid < 6144) {
        int tid = bid * 256 + threadIdx.x;
        int row = tid / 96;
        int c8  = (tid % 96) * 8;
        const float* src; int c;
        if (c8 < NF)            { src = q; c = c8; }
        else if (c8 < 2 * NF)   { src = k; c = c8 - NF; }
        else                    { src = v; c = c8 - 2 * NF; }
        const float4* p = reinterpret_cast<const float4*>(src + (size_t)row * NF + c);
        float4 a = p[0], b = p[1];
        u16x8 o;
        o[0] = bf16_rne(a.x); o[1] = bf16_rne(a.y); o[2] = bf16_rne(a.z); o[3] = bf16_rne(a.w);
        o[4] = bf16_rne(b.x); o[5] = bf16_rne(b.y); o[6] = bf16_rne(b.z); o[7] = bf16_rne(b.w);
        *reinterpret_cast<u16x8*>(xcat + (size_t)row * NTF + c8) = o;
    } else if (bid < 6464) {
        int tid = (bid - 6144) * 256 + threadIdx.x;
        int i8 = tid * 8;
        const float* src; u16* dst; int off;
        if (i8 < NTF * NTF) { src = wqkv; dst = wqkvb; off = i8; }
        else                { src = wout; dst = woutb; off = i8 - NTF * NTF; }
        const float4* p = reinterpret_cast<const float4*>(src + off);
        float4 a = p[0], b = p[1];
        u16x8 o;
        o[0] = bf16_rne(a.x); o[1] = bf16_rne(a.y); o[2] = bf16_rne(a.z); o[3] = bf16_rne(a.w);
        o[4] = bf16_rne(b.x); o[5] = bf16_rne(b.y); o[6] = bf16_rne(b.z); o[7] = bf16_rne(b.w);
        *reinterpret_cast<u16x8*>(dst + off) = o;
    } else {
        int i = (bid - 6464) * 2048 + threadIdx.x * 8;
        int4 m0 = *reinterpret_cast<const int4*>(mask + i);
        int4 m1 = *reinterpret_cast<const int4*>(mask + i + 4);
        float4 f0 = { m0.x ? 0.f : -1e30f, m0.y ? 0.f : -1e30f,
                      m0.z ? 0.f : -1e30f, m0.w ? 0.f : -1e30f };
        float4 f1 = { m1.x ? 0.f : -1e30f, m1.y ? 0.f : -1e30f,
                      m1.z ? 0.f : -1e30f, m1.w ? 0.f : -1e30f };
        *reinterpret_cast<float4*>(maskadd + i) = f0;
        *reinterpret_cast<float4*>(maskadd + i + 4) = f1;
    }
}

// ---------------------------------------------------------------- 128x128 GEMM
// C(MxN) = A(MxK, bf16) * W(NxK)^T + bias. BK=64, 4 waves (2x2), 16x16x32
// MFMA, glds16 dbuf, 1 barrier/k-step. MODE 1: fp32 row-major out.
// MODE 2 (QKV): V 64-col groups scatter transposed to Vt; Q/K row-major u16.
template<int N, int K, int MODE>
__global__ __launch_bounds__(256) void gemm128_kernel(
        const u16* __restrict__ A, const u16* __restrict__ Bw,
        const float* __restrict__ bias, void* __restrict__ Cout,
        u16* __restrict__ Vt) {
    __shared__ alignas(16) char smem[65536];
    char* As = smem;            // 2 x 16KB
    char* Bs = smem + 32768;    // 2 x 16KB
    int m0 = blockIdx.x * 128, n0 = blockIdx.y * 128;
    int tid = threadIdx.x;
    int w = tid >> 6, lane = tid & 63, l15 = lane & 15, hi = lane >> 4;
    int wr = w >> 1, wc = w & 1;
    int r0 = tid >> 3, cb0 = (tid & 7) * 16;       // staging: 32 rows/pass
    int gcb = cb0 ^ ((r0 & 7) << 4);               // pre-swizzled source col-byte
    int wo = w * 1024;

    const char* Ac = (const char*)A;
    const char* Bc = (const char*)Bw;
    const char* gA = Ac + (size_t)(m0 + r0) * (K * 2) + gcb;   // + p*32 rows
    const char* gB = Bc + (size_t)(n0 + r0) * (K * 2) + gcb;
    const size_t rstep = (size_t)32 * (K * 2);     // 32-row pass stride

    // prologue: stage kt=0 into buf 0 (4 passes each for A and B)
#pragma unroll
    for (int p = 0; p < 4; ++p) {
        glds16(gA + p * rstep, As + p * 4096 + wo);
        glds16(gB + p * rstep, Bs + p * 4096 + wo);
    }

    f32x4 acc[4][4];
#pragma unroll
    for (int fi = 0; fi < 4; ++fi)
#pragma unroll
        for (int fj = 0; fj < 4; ++fj) acc[fi][fj] = (f32x4){0.f, 0.f, 0.f, 0.f};

    constexpr int NKT = K / 64;
    for (int kt = 0; kt < NKT; ++kt) {
        int cur = kt & 1;
        __syncthreads();                           // drain glds(kt) + prior reads
        if (kt + 1 < NKT) {
            int off = (kt + 1) * 128;
            char* Ad = As + (cur ^ 1) * 16384;
            char* Bd = Bs + (cur ^ 1) * 16384;
#pragma unroll
            for (int p = 0; p < 4; ++p) {
                glds16(gA + p * rstep + off, Ad + p * 4096 + wo);
                glds16(gB + p * rstep + off, Bd + p * 4096 + wo);
            }
        }
        const char* Ax = As + cur * 16384;
        const char* Bx = Bs + cur * 16384;
#pragma unroll
        for (int ks = 0; ks < 2; ++ks) {
            bf16x8 af[4], bf[4];
#pragma unroll
            for (int fi = 0; fi < 4; ++fi)
                af[fi] = *reinterpret_cast<const bf16x8*>(
                    Ax + swz(wr * 64 + fi * 16 + l15, hi * 16 + ks * 64));
#pragma unroll
            for (int fj = 0; fj < 4; ++fj)
                bf[fj] = *reinterpret_cast<const bf16x8*>(
                    Bx + swz(wc * 64 + fj * 16 + l15, hi * 16 + ks * 64));
#pragma unroll
            for (int fi = 0; fi < 4; ++fi)
#pragma unroll
                for (int fj = 0; fj < 4; ++fj)
                    acc[fi][fj] = mfma16(af[fi], bf[fj], acc[fi][fj]);
        }
    }

    // epilogue
    int rowBase = m0 + wr * 64;        // 64-aligned; never crosses a batch
    if constexpr (MODE == 2) {
        int g64 = (n0 >> 6) + wc;      // 64-col group 0..11
        int typ = g64 % 3, h = g64 / 3;
        if (typ == 2) {
            int b = rowBase >> 11;
            int bh = b * NH + h;
#pragma unroll
            for (int fi = 0; fi < 4; ++fi) {
                int t = (rowBase + fi * 16 + hi * 4) & (NT - 1);
#pragma unroll
                for (int fj = 0; fj < 4; ++fj) {
                    int d = fj * 16 + l15;
                    float bv = bias[n0 + wc * 64 + d];
                    u32 lo = pkbf16(acc[fi][fj][0] + bv, acc[fi][fj][1] + bv);
                    u32 hi2 = pkbf16(acc[fi][fj][2] + bv, acc[fi][fj][3] + bv);
                    u64 pk = (u64)lo | ((u64)hi2 << 32);
                    *reinterpret_cast<u64*>(Vt + (size_t)(bh * 64 + d) * NT + t) = pk;
                }
            }
        } else {
#pragma unroll
            for (int fi = 0; fi < 4; ++fi) {
                int orow = rowBase + fi * 16 + hi * 4;
#pragma unroll
                for (int fj = 0; fj < 4; ++fj) {
                    int col = n0 + wc * 64 + fj * 16 + l15;
                    float bv = bias[col];
#pragma unroll
                    for (int r = 0; r < 4; ++r)
                        reinterpret_cast<u16*>(Cout)[(size_t)(orow + r) * N + col] =
                            bf16_rne(acc[fi][fj][r] + bv);
                }
            }
        }
    } else {
#pragma unroll
        for (int fi = 0; fi < 4; ++fi) {
            int orow = rowBase + fi * 16 + hi * 4;
#pragma unroll
            for (int fj = 0; fj < 4; ++fj) {
                int col = n0 + wc * 64 + fj * 16 + l15;
                float bv = bias[col];
#pragma unroll
                for (int r = 0; r < 4; ++r)
                    reinterpret_cast<float*>(Cout)[(size_t)(orow + r) * N + col] =
                        acc[fi][fj][r] + bv;
            }
        }
    }
}

// ---------------------------------------------------------------- attention
// grid (B*H, T/128): QBLK=128, 512 blocks, 4 waves. Each wave: 64 q-rows
// (wq=w&1 -> two 32-q subtiles) x 32-key half (g=w>>1). Every K/V A-fragment
// feeds TWO MFMAs (both q-subtiles) -> ds_read/MFMA = 0.5. 32x32x16 MFMA;
// swapped QK^T; P in registers (cvt_pk + permlane32_swap); fixed-offset exp2
// softmax. K/V glds16 double-buffer (32KB), 1 barrier/tile. Pair-combine
// epilogue (g=1 partials via LDS). All accumulators statically named.
__global__ __launch_bounds__(256, 3) void attn_kernel(
        const u16* __restrict__ qkv, const u16* __restrict__ vt,
        const float* __restrict__ maskadd, u16* __restrict__ xout) {
    int bh = blockIdx.x;
    int q0 = blockIdx.y * 128;
    int b = bh >> 2, h = bh & 3;
    // K: [0,16384) 2x8KB dbuf; V: [16384,32768) 2x8KB dbuf; sS: [32768,33280)
    __shared__ alignas(16) char smem[33280];
    int tid = threadIdx.x;
    int w = tid >> 6, lane = tid & 63;
    int l31 = lane & 31, hv = lane >> 5;
    int wq = w & 1, g = w >> 1;
    int r0 = tid >> 3, cb0 = (tid & 7) * 16;
    int gcb = cb0 ^ ((r0 & 7) << 4);
    int wo = w * 1024;
    const float SCALE = 0.125f * 1.44269504088896340736f;  // 1/sqrt(dk)*log2e

    const char* qkvC = (const char*)qkv;
    const char* vtC  = (const char*)vt;
    const char* gk0 = qkvC + (size_t)(b * NT + r0) * 1536 + h * 384 + 128 + gcb;
    const char* gv0 = vtC + (size_t)(bh * 64 + r0) * (NT * 2) + gcb;
    const float* gm = maskadd + (size_t)b * NT;

    // prologue: stage tile 0 (K and V, rows r0 / r0+32) into dbuf 0
    glds16(gk0,              smem + wo);
    glds16(gk0 + 32 * 1536,  smem + 4096 + wo);
    glds16(gv0,              smem + 16384 + wo);
    glds16(gv0 + 32 * 4096,  smem + 16384 + 4096 + wo);

    // Q fragments for BOTH 32-q subtiles: B[k=hv*8+j][q=l31] per 16-dk slice
    const char* qrow0 = qkvC + (size_t)(b * NT + q0 + wq * 64 + l31) * 1536
                        + h * 384 + hv * 16;
    const char* qrow1 = qrow0 + (size_t)32 * 1536;
    bf16x8 bQ00 = *reinterpret_cast<const bf16x8*>(qrow0);
    bf16x8 bQ01 = *reinterpret_cast<const bf16x8*>(qrow0 + 32);
    bf16x8 bQ02 = *reinterpret_cast<const bf16x8*>(qrow0 + 64);
    bf16x8 bQ03 = *reinterpret_cast<const bf16x8*>(qrow0 + 96);
    bf16x8 bQ10 = *reinterpret_cast<const bf16x8*>(qrow1);
    bf16x8 bQ11 = *reinterpret_cast<const bf16x8*>(qrow1 + 32);
    bf16x8 bQ12 = *reinterpret_cast<const bf16x8*>(qrow1 + 64);
    bf16x8 bQ13 = *reinterpret_cast<const bf16x8*>(qrow1 + 96);

    // accumulators: acc<sub><dhalf>, O^T[d][q]
    f32x16 acc00 = 0.f, acc01 = 0.f, acc10 = 0.f, acc11 = 0.f;
    float ssum0 = 0.f, ssum1 = 0.f;

    for (int j = 0; j < NT / 64; ++j) {
        int cur = j & 1;
        __syncthreads();   // drains glds(tile j) + prior reads of dbuf cur^1
        if (j < NT / 64 - 1) {
            char* Kd = smem + (cur ^ 1) * 8192;
            char* Vd = smem + 16384 + (cur ^ 1) * 8192;
            size_t ko = (size_t)(j + 1) * 98304;
            size_t vo2 = (size_t)(j + 1) * 128;
            glds16(gk0 + ko,              Kd + wo);
            glds16(gk0 + ko + 32 * 1536,  Kd + 4096 + wo);
            glds16(gv0 + vo2,             Vd + wo);
            glds16(gv0 + vo2 + 32 * 4096, Vd + 4096 + wo);
        }
        const char* Kx = smem + cur * 8192;
        const char* Vx = smem + 16384 + cur * 8192;
        const float* mt = gm + j * 64;

        // ---- QK: each K A-frag feeds both q-subtiles.
        // S^T[key = g*32 + 8rq+4hv+e][q = l31 (+sub*32)]
        f32x16 s0 = 0.f, s1 = 0.f;
        __builtin_amdgcn_s_setprio(1);
#pragma unroll
        for (int ks = 0; ks < 4; ++ks) {
            bf16x8 a = *reinterpret_cast<const bf16x8*>(
                Kx + swz(g * 32 + l31, ks * 32 + hv * 16));
            bf16x8 bq0 = (ks == 0) ? bQ00 : (ks == 1) ? bQ01 : (ks == 2) ? bQ02 : bQ03;
            bf16x8 bq1 = (ks == 0) ? bQ10 : (ks == 1) ? bQ11 : (ks == 2) ? bQ12 : bQ13;
            s0 = mfma32(a, bq0, s0);
            s1 = mfma32(a, bq1, s1);
        }
        __builtin_amdgcn_s_setprio(0);

        // ---- softmax both subtiles: p = 2^(s*SCALE + madd[key]); mask shared
#pragma unroll
        for (int rq = 0; rq < 4; ++rq) {
            f32x4 md = *reinterpret_cast<const f32x4*>(mt + g * 32 + rq * 8 + 4 * hv);
#pragma unroll
            for (int e = 0; e < 4; ++e) {
                s0[rq * 4 + e] = __builtin_amdgcn_exp2f(
                    __builtin_fmaf(s0[rq * 4 + e], SCALE, md[e]));
                s1[rq * 4 + e] = __builtin_amdgcn_exp2f(
                    __builtin_fmaf(s1[rq * 4 + e], SCALE, md[e]));
            }
        }
        {   // per-lane partial row-sums (q differs per subtile)
            union { f32x16 v; f32x4 q[4]; } u0, u1; u0.v = s0; u1.v = s1;
            f32x4 r0v = (u0.q[0] + u0.q[1]) + (u0.q[2] + u0.q[3]);
            f32x4 r1v = (u1.q[0] + u1.q[1]) + (u1.q[2] + u1.q[3]);
            ssum0 += (r0v[0] + r0v[1]) + (r0v[2] + r0v[3]);
            ssum1 += (r1v[0] + r1v[1]) + (r1v[2] + r1v[3]);
        }
        // ---- pack P (both subtiles)
        u32 pa0[4], pb0[4], pa1[4], pb1[4];
#pragma unroll
        for (int rq = 0; rq < 4; ++rq) {
            pa0[rq] = pkbf16(s0[rq * 4 + 0], s0[rq * 4 + 1]);
            pb0[rq] = pkbf16(s0[rq * 4 + 2], s0[rq * 4 + 3]);
            pa1[rq] = pkbf16(s1[rq * 4 + 0], s1[rq * 4 + 1]);
            pb1[rq] = pkbf16(s1[rq * 4 + 2], s1[rq * 4 + 3]);
        }
        // ---- PV: each V A-frag pair feeds both subtiles' MFMAs
        __builtin_amdgcn_s_setprio(1);
#pragma unroll
        for (int sp2 = 0; sp2 < 2; ++sp2) {
            const int sp = sp2 * 2;
            int s4 = 2 * g + sp2;
            bf16x8 av0 = *reinterpret_cast<const bf16x8*>(
                Vx + swz(l31, s4 * 32 + hv * 16));
            bf16x8 av1 = *reinterpret_cast<const bf16x8*>(
                Vx + swz(32 + l31, s4 * 32 + hv * 16));
            // subtile 0 B-operand
            u32 A0 = pa0[sp], A2 = pa0[sp + 1], A1 = pb0[sp], A3 = pb0[sp + 1];
            pl32swap(A0, A2);
            pl32swap(A1, A3);
            union { u32 u4[4]; bf16x8 v; } bp0;
            bp0.u4[0] = A0; bp0.u4[1] = A1; bp0.u4[2] = A2; bp0.u4[3] = A3;
            // subtile 1 B-operand
            u32 C0 = pa1[sp], C2 = pa1[sp + 1], C1 = pb1[sp], C3 = pb1[sp + 1];
            pl32swap(C0, C2);
            pl32swap(C1, C3);
            union { u32 u4[4]; bf16x8 v; } bp1;
            bp1.u4[0] = C0; bp1.u4[1] = C1; bp1.u4[2] = C2; bp1.u4[3] = C3;
            acc00 = mfma32(av0, bp0.v, acc00);
            acc01 = mfma32(av1, bp0.v, acc01);
            acc10 = mfma32(av0, bp1.v, acc10);
            acc11 = mfma32(av1, bp1.v, acc11);
        }
        __builtin_amdgcn_s_setprio(0);
    }

    // ---- combine key-half pairs: g=1 hands partials to g=0 via LDS.
    // region per (wq,sub): 8KB = 8 x f32x4 chunks x 64 lanes.
    ssum0 += __shfl_xor(ssum0, 32, 64);
    ssum1 += __shfl_xor(ssum1, 32, 64);
    __syncthreads();   // all K/V LDS reads done; LDS reusable
    float* sS = reinterpret_cast<float*>(smem + 32768);
    if (g == 1) {
        union { f32x16 v; f32x4 q[4]; } a00, a01, a10, a11;
        a00.v = acc00; a01.v = acc01; a10.v = acc10; a11.v = acc11;
#pragma unroll
        for (int i = 0; i < 4; ++i) {
            *reinterpret_cast<f32x4*>(smem + (wq * 2 + 0) * 8192 + i * 1024 + lane * 16) = a00.q[i];
            *reinterpret_cast<f32x4*>(smem + (wq * 2 + 0) * 8192 + (4 + i) * 1024 + lane * 16) = a01.q[i];
            *reinterpret_cast<f32x4*>(smem + (wq * 2 + 1) * 8192 + i * 1024 + lane * 16) = a10.q[i];
            *reinterpret_cast<f32x4*>(smem + (wq * 2 + 1) * 8192 + (4 + i) * 1024 + lane * 16) = a11.q[i];
        }
        if (lane < 32) {
            sS[(wq * 2 + 0) * 32 + l31] = ssum0;
            sS[(wq * 2 + 1) * 32 + l31] = ssum1;
        }
    }
    __syncthreads();
    if (g == 0) {
        union { f32x16 v; f32x4 q[4]; } a00, a01, a10, a11;
        a00.v = acc00; a01.v = acc01; a10.v = acc10; a11.v = acc11;
#pragma unroll
        for (int i = 0; i < 4; ++i) {
            a00.q[i] += *reinterpret_cast<const f32x4*>(smem + (wq * 2 + 0) * 8192 + i * 1024 + lane * 16);
            a01.q[i] += *reinterpret_cast<const f32x4*>(smem + (wq * 2 + 0) * 8192 + (4 + i) * 1024 + lane * 16);
            a10.q[i] += *reinterpret_cast<const f32x4*>(smem + (wq * 2 + 1) * 8192 + i * 1024 + lane * 16);
            a11.q[i] += *reinterpret_cast<const f32x4*>(smem + (wq * 2 + 1) * 8192 + (4 + i) * 1024 + lane * 16);
        }
        float st0 = ssum0 + sS[(wq * 2 + 0) * 32 + l31];
        float st1 = ssum1 + sS[(wq * 2 + 1) * 32 + l31];
        float inv0 = st0 > 0.f ? 1.0f / st0 : 0.0f;
        float inv1 = st1 > 0.f ? 1.0f / st1 : 0.0f;
        int qg0 = b * NT + q0 + wq * 64 + l31;
        int qg1 = qg0 + 32;
        const float* f00 = (const float*)&a00.v;
        const float* f01 = (const float*)&a01.v;
        const float* f10 = (const float*)&a10.v;
        const float* f11 = (const float*)&a11.v;
#pragma unroll
        for (int rq = 0; rq < 4; ++rq) {
            int d0 = rq * 8 + 4 * hv;
            u64 pk;
            pk = (u64)pkbf16(f00[rq * 4 + 0] * inv0, f00[rq * 4 + 1] * inv0)
               | ((u64)pkbf16(f00[rq * 4 + 2] * inv0, f00[rq * 4 + 3] * inv0) << 32);
            *reinterpret_cast<u64*>(xout + (size_t)qg0 * NF + h * 64 + d0) = pk;
            pk = (u64)pkbf16(f01[rq * 4 + 0] * inv0, f01[rq * 4 + 1] * inv0)
               | ((u64)pkbf16(f01[rq * 4 + 2] * inv0, f01[rq * 4 + 3] * inv0) << 32);
            *reinterpret_cast<u64*>(xout + (size_t)qg0 * NF + h * 64 + 32 + d0) = pk;
            pk = (u64)pkbf16(f10[rq * 4 + 0] * inv1, f10[rq * 4 + 1] * inv1)
               | ((u64)pkbf16(f10[rq * 4 + 2] * inv1, f10[rq * 4 + 3] * inv1) << 32);
            *reinterpret_cast<u64*>(xout + (size_t)qg1 * NF + h * 64 + d0) = pk;
            pk = (u64)pkbf16(f11[rq * 4 + 0] * inv1, f11[rq * 4 + 1] * inv1)
               | ((u64)pkbf16(f11[rq * 4 + 2] * inv1, f11[rq * 4 + 3] * inv1) << 32);
            *reinterpret_cast<u64*>(xout + (size_t)qg1 * NF + h * 64 + 32 + d0) = pk;
        }
    }
}

// ---------------------------------------------------------------- launch
extern "C" void kernel_launch(void* const* d_in, const int* in_sizes, int n_in,
                              void* d_out, int out_size, void* d_ws, size_t ws_size,
                              hipStream_t stream) {
    const float* q    = (const float*)d_in[0];
    const float* k    = (const float*)d_in[1];
    const float* v    = (const float*)d_in[2];
    const int*   mask = (const int*)d_in[3];
    const float* wqkv = (const float*)d_in[4];
    const float* bqkv = (const float*)d_in[5];
    const float* wout = (const float*)d_in[6];
    const float* bout = (const float*)d_in[7];
    float* out = (float*)d_out;

    char* ws = (char*)d_ws;
    u16*   Xcat    = (u16*)(ws);                   // 25,165,824 B
    u16*   QKV     = (u16*)(ws + 25165824);        // 25,165,824 B (V cols unused)
    u16*   Vt      = (u16*)(ws + 50331648);        //  8,388,608 B
    u16*   Xattn   = (u16*)(ws + 58720256);        //  8,388,608 B
    u16*   Wqkvb   = (u16*)(ws + 67108864);        //  1,179,648 B
    u16*   Woutb   = (u16*)(ws + 68288512);        //    131,072 B
    float* Maskadd = (float*)(ws + 68419584);      //     65,536 B

    convert_all_kernel<<<6472, 256, 0, stream>>>(q, k, v, wqkv, wout, mask,
                                                 Xcat, Wqkvb, Woutb, Maskadd);
    gemm128_kernel<NTF, NTF, 2><<<dim3(NM / 128, NTF / 128), 256, 0, stream>>>(
        Xcat, Wqkvb, bqkv, QKV, Vt);
    attn_kernel<<<dim3(NB * NH, NT / 128), 256, 0, stream>>>(QKV, Vt, Maskadd, Xattn);
    gemm128_kernel<NF, NF, 1><<<dim3(NM / 128, NF / 128), 256, 0, stream>>>(
        Xattn, Woutb, bout, out, nullptr);
}